// Round 3
// baseline (230.042 us; speedup 1.0000x reference)
//
#include <hip/hip_runtime.h>
#include <hip/hip_bf16.h>

// Shapes: bz=32, rv_num=10, rv_len=128, in_feat=300, out_feat=128
// N = 320 reviews, tokens per side = 40960, M = 1280 tokens/sample.

#define K_FEAT 300
#define H 128
#define NTOK 40960          // tokens per side
#define NREV 320            // reviews per side
#define TOK_PER_SAMPLE 1280
#define KC 30               // K-chunk for fc (10 chunks)
#define FCTM 128            // tokens per fc block

// ---------------- Kernel 0: zero the mean accumulators ----------------
__global__ void zero_kernel(float* __restrict__ p, int n)
{
    int i = blockIdx.x * blockDim.x + threadIdx.x;
    if (i < n) p[i] = 0.f;
}

// ---------------- Kernel 1: FC + ReLU (fp32, 8x8 micro-tile) + fused mean ----------------
// grid.x = 640 (320 side a, 320 side b); block = 256. Tile: 128 tokens x 128 feats.
// Thread (fx = tid&15 -> 8 feats, ty = tid>>4 -> 8 tokens).
__global__ __launch_bounds__(256, 4) void fc_relu_kernel(
    const float* __restrict__ seq_a, const float* __restrict__ seq_b,
    const float* __restrict__ W, const float* __restrict__ bias,
    float* __restrict__ ta, float* __restrict__ tb,
    float* __restrict__ msum_a, float* __restrict__ msum_b)
{
    __shared__ float A_s[FCTM * (KC + 1)];  // [token][k], pad 31 -> ty-groups land on distinct banks
    __shared__ float W_s[KC * H];           // [k][h]
    __shared__ float msum_s[H];

    int blk = blockIdx.x;
    const float* seq;
    float* outp;
    float* msum;
    if (blk < 320) { seq = seq_a; outp = ta; msum = msum_a; }
    else           { seq = seq_b; outp = tb; msum = msum_b; blk -= 320; }

    const int tid = threadIdx.x;
    const int tok0 = blk * FCTM;
    const int sample = tok0 / TOK_PER_SAMPLE;   // 10 blocks per sample
    const int fx = tid & 15;    // feature group: h = fx*8 .. fx*8+7
    const int ty = tid >> 4;    // token group: tokens ty*8 .. ty*8+7

    if (tid < H) msum_s[tid] = 0.f;

    float acc[8][8];
#pragma unroll
    for (int r = 0; r < 8; ++r)
#pragma unroll
        for (int c = 0; c < 8; ++c) acc[r][c] = 0.f;

    for (int k0 = 0; k0 < K_FEAT; k0 += KC) {
        // Stage A: 128 tokens x 15 float2 (KC=30 floats). k0*4 bytes is 8B-aligned (120B).
        for (int i = tid; i < FCTM * (KC / 2); i += 256) {
            int tok = i / 15;
            int j = i - tok * 15;
            float2 v = *(const float2*)&seq[(size_t)(tok0 + tok) * K_FEAT + k0 + 2 * j];
            A_s[tok * (KC + 1) + 2 * j]     = v.x;
            A_s[tok * (KC + 1) + 2 * j + 1] = v.y;
        }
        // Stage W: 30 rows x 32 float4
        for (int i = tid; i < KC * (H / 4); i += 256) {
            int k = i >> 5;
            int h4 = i & 31;
            float4 v = *(const float4*)&W[(size_t)(k0 + k) * H + h4 * 4];
            *(float4*)&W_s[k * H + h4 * 4] = v;
        }
        __syncthreads();

#pragma unroll 2
        for (int k = 0; k < KC; ++k) {
            float4 w0 = *(const float4*)&W_s[k * H + fx * 8];
            float4 w1 = *(const float4*)&W_s[k * H + fx * 8 + 4];
            float a[8];
#pragma unroll
            for (int r = 0; r < 8; ++r) a[r] = A_s[(ty * 8 + r) * (KC + 1) + k];
#pragma unroll
            for (int r = 0; r < 8; ++r) {
                acc[r][0] = fmaf(a[r], w0.x, acc[r][0]);
                acc[r][1] = fmaf(a[r], w0.y, acc[r][1]);
                acc[r][2] = fmaf(a[r], w0.z, acc[r][2]);
                acc[r][3] = fmaf(a[r], w0.w, acc[r][3]);
                acc[r][4] = fmaf(a[r], w1.x, acc[r][4]);
                acc[r][5] = fmaf(a[r], w1.y, acc[r][5]);
                acc[r][6] = fmaf(a[r], w1.z, acc[r][6]);
                acc[r][7] = fmaf(a[r], w1.w, acc[r][7]);
            }
        }
        __syncthreads();
    }

    // Epilogue: bias + ReLU + store + per-feature sums for the mean
    float4 bb0 = *(const float4*)&bias[fx * 8];
    float4 bb1 = *(const float4*)&bias[fx * 8 + 4];
    float fsum[8] = {0.f, 0.f, 0.f, 0.f, 0.f, 0.f, 0.f, 0.f};
#pragma unroll
    for (int r = 0; r < 8; ++r) {
        int tok = tok0 + ty * 8 + r;
        float4 v0, v1;
        v0.x = fmaxf(acc[r][0] + bb0.x, 0.f);
        v0.y = fmaxf(acc[r][1] + bb0.y, 0.f);
        v0.z = fmaxf(acc[r][2] + bb0.z, 0.f);
        v0.w = fmaxf(acc[r][3] + bb0.w, 0.f);
        v1.x = fmaxf(acc[r][4] + bb1.x, 0.f);
        v1.y = fmaxf(acc[r][5] + bb1.y, 0.f);
        v1.z = fmaxf(acc[r][6] + bb1.z, 0.f);
        v1.w = fmaxf(acc[r][7] + bb1.w, 0.f);
        fsum[0] += v0.x; fsum[1] += v0.y; fsum[2] += v0.z; fsum[3] += v0.w;
        fsum[4] += v1.x; fsum[5] += v1.y; fsum[6] += v1.z; fsum[7] += v1.w;
        *(float4*)&outp[(size_t)tok * H + fx * 8]     = v0;
        *(float4*)&outp[(size_t)tok * H + fx * 8 + 4] = v1;
    }
#pragma unroll
    for (int c = 0; c < 8; ++c)
        atomicAdd(&msum_s[fx * 8 + c], fsum[c]);
    __syncthreads();
    if (tid < H) atomicAdd(&msum[sample * H + tid], msum_s[tid]);
}

// ---------------- Kernel 2: scores -> masked softmax -> weighted sum ----------------
// grid.x = 640 (320 reviews x 2 sides); block = 256. No LDS tile: scores computed
// during a coalesced float4 streaming pass; output pass re-reads rows coalesced (L2/L3 hot).
__global__ __launch_bounds__(256) void attn_kernel(
    const float* __restrict__ ta, const float* __restrict__ tb,
    const int* __restrict__ mask_a, const int* __restrict__ mask_b,
    const float* __restrict__ msum_a, const float* __restrict__ msum_b,
    float* __restrict__ out)
{
    int n = blockIdx.x;
    int side = 0;
    if (n >= NREV) { side = 1; n -= NREV; }

    const float* t = side ? tb : ta;
    const int* mask = side ? mask_b : mask_a;
    const float* mean_o = side ? msum_a : msum_b;  // raw sums of the OTHER side
    float* out_vec = out + (side ? NREV * H : 0);              // a_out / b_out
    float* out_w = out + 2 * NREV * H + (side ? NREV * H : 0); // atob_w / btoa_w

    int sample = n / 10;
    int tid = threadIdx.x;

    __shared__ float score_part[128 * 33];  // [row][col-group], pad 33 -> conflict-free
    __shared__ float mean_s[128];
    __shared__ float w_s[128];
    __shared__ float red[4];
    __shared__ float part_out[8 * 128];

    if (tid < 128) mean_s[tid] = mean_o[sample * H + tid] * (1.0f / (float)TOK_PER_SAMPLE);
    __syncthreads();

    const float* rowbase = t + (size_t)n * 128 * H;

    // Phase 1: streaming score partials. q-th float4 of the 128x128 tile.
#pragma unroll
    for (int i = 0; i < 16; ++i) {
        int q = tid + 256 * i;          // 0..4095
        int r = q >> 5;                 // row
        int c4 = q & 31;                // float4 within row
        float4 v = *(const float4*)&rowbase[q * 4];
        float4 m = *(const float4*)&mean_s[c4 * 4];
        score_part[r * 33 + c4] = v.x * m.x + v.y * m.y + v.z * m.z + v.w * m.w;
    }
    __syncthreads();

    // Phase 2: row sums -> masked softmax
    float logit = -1e9f;
    if (tid < 128) {
        float s = 0.f;
#pragma unroll
        for (int j = 0; j < 32; ++j) s += score_part[tid * 33 + j];
        int mv = mask[n * 128 + tid];
        logit = (mv > 0) ? s : -1e9f;
    }

    float mx = logit;
    for (int off = 32; off > 0; off >>= 1) mx = fmaxf(mx, __shfl_xor(mx, off));
    if ((tid & 63) == 0) red[tid >> 6] = mx;
    __syncthreads();
    mx = fmaxf(fmaxf(red[0], red[1]), fmaxf(red[2], red[3]));
    __syncthreads();

    float e = __expf(logit - mx);
    float ssum = e;
    for (int off = 32; off > 0; off >>= 1) ssum += __shfl_xor(ssum, off);
    if ((tid & 63) == 0) red[tid >> 6] = ssum;
    __syncthreads();
    ssum = red[0] + red[1] + red[2] + red[3];

    float w = e / ssum;
    if (tid < 128) {
        w_s[tid] = w;
        out_w[n * 128 + tid] = w;
    }
    __syncthreads();

    // Phase 3: out[d] = sum_l w_l * row_l[d], rows re-read coalesced from global.
    int c4 = tid & 31;   // float4 column group
    int lp = tid >> 5;   // l-partition (8)
    float4 o4 = make_float4(0.f, 0.f, 0.f, 0.f);
#pragma unroll
    for (int k = 0; k < 16; ++k) {
        int l = k * 8 + lp;
        float wl = w_s[l];
        float4 v = *(const float4*)&rowbase[(size_t)l * H + c4 * 4];
        o4.x = fmaf(wl, v.x, o4.x);
        o4.y = fmaf(wl, v.y, o4.y);
        o4.z = fmaf(wl, v.z, o4.z);
        o4.w = fmaf(wl, v.w, o4.w);
    }
    *(float4*)&part_out[lp * 128 + c4 * 4] = o4;
    __syncthreads();
    if (tid < 128) {
        float o = 0.f;
#pragma unroll
        for (int p = 0; p < 8; ++p) o += part_out[p * 128 + tid];
        out_vec[n * 128 + tid] = o;
    }
}

// ---------------- Launch ----------------
extern "C" void kernel_launch(void* const* d_in, const int* in_sizes, int n_in,
                              void* d_out, int out_size, void* d_ws, size_t ws_size,
                              hipStream_t stream)
{
    const float* seq_a = (const float*)d_in[0];
    const float* seq_b = (const float*)d_in[1];
    const int* mask_a = (const int*)d_in[2];
    const int* mask_b = (const int*)d_in[3];
    const float* W = (const float*)d_in[4];
    const float* bias = (const float*)d_in[5];
    float* out = (float*)d_out;

    float* ws = (float*)d_ws;
    float* ta = ws;                          // 40960*128
    float* tb = ta + (size_t)NTOK * H;       // 40960*128
    float* msum_a = tb + (size_t)NTOK * H;   // 32*128 raw sums
    float* msum_b = msum_a + 32 * H;         // 32*128

    zero_kernel<<<(2 * 32 * H + 255) / 256, 256, 0, stream>>>(msum_a, 2 * 32 * H);
    fc_relu_kernel<<<640, 256, 0, stream>>>(seq_a, seq_b, W, bias, ta, tb, msum_a, msum_b);
    attn_kernel<<<640, 256, 0, stream>>>(ta, tb, mask_a, mask_b, msum_a, msum_b, out);
}

// Round 4
// 169.222 us; speedup vs baseline: 1.3594x; 1.3594x over previous
//
#include <hip/hip_runtime.h>
#include <hip/hip_bf16.h>

// Shapes: bz=32, rv_num=10, rv_len=128, in_feat=300, out_feat=128
// N = 320 reviews, tokens/side = 40960, M = 1280 tokens/sample.

#define K_FEAT 300
#define KP 320              // K padded to 10 chunks of 32
#define H 128
#define NTOK 40960
#define NREV 320
#define TOK_PER_SAMPLE 1280
#define TM 64               // tokens per fc block
#define BLKS_PER_SAMPLE (TOK_PER_SAMPLE / TM)   // 20
#define LDA 40              // LDS row stride (bf16 elems) for 32-k chunk, +8 pad

typedef __attribute__((ext_vector_type(8))) short bf16x8;
typedef __attribute__((ext_vector_type(4))) float f32x4;

static __device__ __forceinline__ unsigned short f2bf(float x) {
    unsigned int u = __float_as_uint(x);
    unsigned int r = (u + 0x7fffu + ((u >> 16) & 1u)) >> 16;
    return (unsigned short)r;
}
static __device__ __forceinline__ float bf2f(unsigned short s) {
    return __uint_as_float(((unsigned int)s) << 16);
}

// ---------------- Kernel 0: split W into bf16 hi/lo, transposed + K-padded ----------------
// W[k][h] fp32 -> Wh_t[h][KP], Wl_t[h][KP] bf16. grid 160 x 256.
__global__ void wsplit_kernel(const float* __restrict__ W,
                              unsigned short* __restrict__ Wh_t,
                              unsigned short* __restrict__ Wl_t)
{
    int i = blockIdx.x * 256 + threadIdx.x;   // 128*320 = 40960
    if (i >= H * KP) return;
    int h = i / KP;
    int k = i - h * KP;
    float w = (k < K_FEAT) ? W[(size_t)k * H + h] : 0.f;
    unsigned short hi = f2bf(w);
    unsigned short lo = f2bf(w - bf2f(hi));
    Wh_t[h * KP + k] = hi;
    Wl_t[h * KP + k] = lo;
}

// ---------------- Kernel 1: FC + ReLU via split-bf16 MFMA + per-block mean partials ----------------
// grid.x = 1280 (640 side a, 640 side b); block = 256 (4 waves). Tile: 64 tokens x 128 feats.
// Wave w owns tokens w*16..w*16+15 of the tile, all 128 features (8 n-tiles).
__global__ __launch_bounds__(256, 4) void fc_mfma_kernel(
    const float* __restrict__ seq_a, const float* __restrict__ seq_b,
    const unsigned short* __restrict__ Wh_t, const unsigned short* __restrict__ Wl_t,
    const float* __restrict__ bias,
    float* __restrict__ ta, float* __restrict__ tb,
    float* __restrict__ psum_a, float* __restrict__ psum_b)
{
    __shared__ unsigned short Ah_s[TM * LDA];     // [tok][k] 64x40
    __shared__ unsigned short Al_s[TM * LDA];
    __shared__ unsigned short Wh_s[H * LDA];      // [h][k] 128x40
    __shared__ unsigned short Wl_s[H * LDA];
    __shared__ float bias_s[H];
    __shared__ float psum_s[H];

    int blk = blockIdx.x;
    const float* seq;
    float* outp;
    float* psum;
    if (blk < 640) { seq = seq_a; outp = ta; psum = psum_a; }
    else           { seq = seq_b; outp = tb; psum = psum_b; blk -= 640; }

    const int tid = threadIdx.x;
    const int tok0 = blk * TM;
    const int wave = tid >> 6;
    const int lane = tid & 63;
    const int nn = lane & 15;       // n' / m' within 16
    const int quad = lane >> 4;     // 0..3

    if (tid < H) { bias_s[tid] = bias[tid]; psum_s[tid] = 0.f; }

    f32x4 acc[8];
#pragma unroll
    for (int nt = 0; nt < 8; ++nt) acc[nt] = (f32x4){0.f, 0.f, 0.f, 0.f};

    for (int c = 0; c < 10; ++c) {
        int k0 = c * 32;
        __syncthreads();
        // Stage A: 64 tok x 32 k fp32 -> bf16 hi/lo. 512 float4 over 256 threads.
#pragma unroll
        for (int it = 0; it < 2; ++it) {
            int i = tid + it * 256;
            int t = i >> 3;
            int j = i & 7;
            int kk = k0 + 4 * j;
            float4 v = make_float4(0.f, 0.f, 0.f, 0.f);
            if (kk + 3 < K_FEAT)
                v = *(const float4*)&seq[(size_t)(tok0 + t) * K_FEAT + kk];
            unsigned short h0 = f2bf(v.x), h1 = f2bf(v.y), h2 = f2bf(v.z), h3 = f2bf(v.w);
            uint2 hp, lp;
            hp.x = (unsigned)h0 | ((unsigned)h1 << 16);
            hp.y = (unsigned)h2 | ((unsigned)h3 << 16);
            lp.x = (unsigned)f2bf(v.x - bf2f(h0)) | ((unsigned)f2bf(v.y - bf2f(h1)) << 16);
            lp.y = (unsigned)f2bf(v.z - bf2f(h2)) | ((unsigned)f2bf(v.w - bf2f(h3)) << 16);
            *(uint2*)&Ah_s[t * LDA + 4 * j] = hp;
            *(uint2*)&Al_s[t * LDA + 4 * j] = lp;
        }
        // Stage W: 128 h x 32 k bf16 (hi and lo). 512 16B-chunks over 256 threads.
#pragma unroll
        for (int it = 0; it < 2; ++it) {
            int i = tid + it * 256;
            int h = i >> 2;
            int j = i & 3;
            uint4 vh = *(const uint4*)&Wh_t[h * KP + k0 + 8 * j];
            uint4 vl = *(const uint4*)&Wl_t[h * KP + k0 + 8 * j];
            *(uint4*)&Wh_s[h * LDA + 8 * j] = vh;
            *(uint4*)&Wl_s[h * LDA + 8 * j] = vl;
        }
        __syncthreads();

        // A-fragments: m = nn, k = quad*8+j
        bf16x8 a_hi = *(const bf16x8*)&Ah_s[(wave * 16 + nn) * LDA + quad * 8];
        bf16x8 a_lo = *(const bf16x8*)&Al_s[(wave * 16 + nn) * LDA + quad * 8];
#pragma unroll
        for (int nt = 0; nt < 8; ++nt) {
            bf16x8 b_hi = *(const bf16x8*)&Wh_s[(nt * 16 + nn) * LDA + quad * 8];
            bf16x8 b_lo = *(const bf16x8*)&Wl_s[(nt * 16 + nn) * LDA + quad * 8];
            acc[nt] = __builtin_amdgcn_mfma_f32_16x16x32_bf16(a_hi, b_hi, acc[nt], 0, 0, 0);
            acc[nt] = __builtin_amdgcn_mfma_f32_16x16x32_bf16(a_hi, b_lo, acc[nt], 0, 0, 0);
            acc[nt] = __builtin_amdgcn_mfma_f32_16x16x32_bf16(a_lo, b_hi, acc[nt], 0, 0, 0);
        }
    }

    // Epilogue: bias + ReLU + store; per-block feature sums (no global atomics).
    // C/D layout: col = nn (feature within n-tile), row m = quad*4 + reg.
#pragma unroll
    for (int nt = 0; nt < 8; ++nt) {
        int hcol = nt * 16 + nn;
        float bv = bias_s[hcol];
        float rsum = 0.f;
#pragma unroll
        for (int reg = 0; reg < 4; ++reg) {
            int tok = tok0 + wave * 16 + quad * 4 + reg;
            float v = fmaxf(acc[nt][reg] + bv, 0.f);
            outp[(size_t)tok * H + hcol] = v;
            rsum += v;
        }
        // reduce over quads (lanes nn, nn+16, nn+32, nn+48 share hcol)
        rsum += __shfl_xor(rsum, 16);
        rsum += __shfl_xor(rsum, 32);
        if (quad == 0) atomicAdd(&psum_s[hcol], rsum);
    }
    __syncthreads();
    if (tid < H) psum[(size_t)blk * H + tid] = psum_s[tid];
}

// ---------------- Kernel 2: scores -> masked softmax -> weighted sum ----------------
// grid.x = 640 (320 reviews x 2 sides); block = 256.
__global__ __launch_bounds__(256) void attn_kernel(
    const float* __restrict__ ta, const float* __restrict__ tb,
    const int* __restrict__ mask_a, const int* __restrict__ mask_b,
    const float* __restrict__ psum_a, const float* __restrict__ psum_b,
    float* __restrict__ out)
{
    int n = blockIdx.x;
    int side = 0;
    if (n >= NREV) { side = 1; n -= NREV; }

    const float* t = side ? tb : ta;
    const int* mask = side ? mask_b : mask_a;
    const float* psum_o = side ? psum_a : psum_b;   // partials of the OTHER side
    float* out_vec = out + (side ? NREV * H : 0);
    float* out_w = out + 2 * NREV * H + (side ? NREV * H : 0);

    int sample = n / 10;
    int tid = threadIdx.x;

    __shared__ float score_part[128 * 33];
    __shared__ float mean_s[128];
    __shared__ float w_s[128];
    __shared__ float red[4];
    __shared__ float part_out[8 * 128];

    if (tid < 128) {
        float s = 0.f;
        const float* pb = psum_o + (size_t)sample * BLKS_PER_SAMPLE * H + tid;
#pragma unroll
        for (int i = 0; i < BLKS_PER_SAMPLE; ++i) s += pb[(size_t)i * H];
        mean_s[tid] = s * (1.0f / (float)TOK_PER_SAMPLE);
    }
    __syncthreads();

    const float* rowbase = t + (size_t)n * 128 * H;

    // Phase 1: streaming score partials (coalesced float4 over the 128x128 tile)
#pragma unroll
    for (int i = 0; i < 16; ++i) {
        int q = tid + 256 * i;
        int r = q >> 5;
        int c4 = q & 31;
        float4 v = *(const float4*)&rowbase[q * 4];
        float4 m = *(const float4*)&mean_s[c4 * 4];
        score_part[r * 33 + c4] = v.x * m.x + v.y * m.y + v.z * m.z + v.w * m.w;
    }
    __syncthreads();

    // Phase 2: row sums -> masked softmax
    float logit = -1e9f;
    if (tid < 128) {
        float s = 0.f;
#pragma unroll
        for (int j = 0; j < 32; ++j) s += score_part[tid * 33 + j];
        int mv = mask[n * 128 + tid];
        logit = (mv > 0) ? s : -1e9f;
    }

    float mx = logit;
    for (int off = 32; off > 0; off >>= 1) mx = fmaxf(mx, __shfl_xor(mx, off));
    if ((tid & 63) == 0) red[tid >> 6] = mx;
    __syncthreads();
    mx = fmaxf(fmaxf(red[0], red[1]), fmaxf(red[2], red[3]));
    __syncthreads();

    float e = __expf(logit - mx);
    float ssum = e;
    for (int off = 32; off > 0; off >>= 1) ssum += __shfl_xor(ssum, off);
    if ((tid & 63) == 0) red[tid >> 6] = ssum;
    __syncthreads();
    ssum = red[0] + red[1] + red[2] + red[3];

    float w = e / ssum;
    if (tid < 128) {
        w_s[tid] = w;
        out_w[n * 128 + tid] = w;
    }
    __syncthreads();

    // Phase 3: out[d] = sum_l w_l * row_l[d] (rows L2/L3-hot)
    int c4 = tid & 31;
    int lp = tid >> 5;
    float4 o4 = make_float4(0.f, 0.f, 0.f, 0.f);
#pragma unroll
    for (int k = 0; k < 16; ++k) {
        int l = k * 8 + lp;
        float wl = w_s[l];
        float4 v = *(const float4*)&rowbase[(size_t)l * H + c4 * 4];
        o4.x = fmaf(wl, v.x, o4.x);
        o4.y = fmaf(wl, v.y, o4.y);
        o4.z = fmaf(wl, v.z, o4.z);
        o4.w = fmaf(wl, v.w, o4.w);
    }
    *(float4*)&part_out[lp * 128 + c4 * 4] = o4;
    __syncthreads();
    if (tid < 128) {
        float o = 0.f;
#pragma unroll
        for (int p = 0; p < 8; ++p) o += part_out[p * 128 + tid];
        out_vec[n * 128 + tid] = o;
    }
}

// ---------------- Launch ----------------
extern "C" void kernel_launch(void* const* d_in, const int* in_sizes, int n_in,
                              void* d_out, int out_size, void* d_ws, size_t ws_size,
                              hipStream_t stream)
{
    const float* seq_a = (const float*)d_in[0];
    const float* seq_b = (const float*)d_in[1];
    const int* mask_a = (const int*)d_in[2];
    const int* mask_b = (const int*)d_in[3];
    const float* W = (const float*)d_in[4];
    const float* bias = (const float*)d_in[5];
    float* out = (float*)d_out;

    float* ws = (float*)d_ws;
    float* ta = ws;                                   // 40960*128
    float* tb = ta + (size_t)NTOK * H;                // 40960*128
    float* psum_a = tb + (size_t)NTOK * H;            // 640*128
    float* psum_b = psum_a + 640 * H;                 // 640*128
    unsigned short* Wh_t = (unsigned short*)(psum_b + 640 * H);  // 128*320 bf16
    unsigned short* Wl_t = Wh_t + H * KP;

    wsplit_kernel<<<(H * KP + 255) / 256, 256, 0, stream>>>(W, Wh_t, Wl_t);
    fc_mfma_kernel<<<1280, 256, 0, stream>>>(seq_a, seq_b, Wh_t, Wl_t, bias,
                                             ta, tb, psum_a, psum_b);
    attn_kernel<<<640, 256, 0, stream>>>(ta, tb, mask_a, mask_b, psum_a, psum_b, out);
}